// Round 3
// baseline (238.945 us; speedup 1.0000x reference)
//
#include <hip/hip_runtime.h>

#define NCELLS (8192 * 7 * 7)   // 401408 = 1568 * 256 exactly
#define BLOCK 256
#define WAVES 4
#define F4PW 480                // 64 cells * 30 floats / 4 per wave per array
#define NSLOT 64                // scatter slots for atomics (64B-padded)

__device__ __forceinline__ float sq(float x) { return x * x; }

__device__ __forceinline__ float iou_fn(const float* t, const float* p, float fi, float fj) {
    const float STEP = 1.0f / 7.0f;
    float w1 = t[2], h1 = t[3];
    float x1 = (t[0] + fj) * STEP, y1 = (t[1] + fi) * STEP;
    float a1 = fmaxf(x1 - w1 * 0.5f, 0.0f);
    float b1 = fmaxf(y1 - h1 * 0.5f, 0.0f);
    float w2 = p[2], h2 = p[3];
    float x2 = (p[0] + fj) * STEP, y2 = (p[1] + fi) * STEP;
    float a2 = fmaxf(x2 - w2 * 0.5f, 0.0f);
    float b2 = fmaxf(y2 - h2 * 0.5f, 0.0f);
    float iw = w1 + w2 - (fmaxf(a1 + w1, a2 + w2) - fminf(a1, a2));
    float ih = h1 + h2 - (fmaxf(b1 + h1, b2 + h2) - fminf(b1, b2));
    bool valid = (iw > 0.0f) && (ih > 0.0f);
    float inter = valid ? iw * ih : 0.0f;
    float uni = w1 * h1 + w2 * h2 - inter;
    return valid ? inter / uni : 0.0f;
}

template <bool USE_WS>
__global__ __launch_bounds__(BLOCK) void yolo_loss_kernel(
        const float4* __restrict__ pred4, const float4* __restrict__ tgt4,
        float* __restrict__ partials, unsigned int* __restrict__ counter,
        float* __restrict__ out, int nticket) {
    // Per-wave private staging segments: no block-wide barrier anywhere.
    __shared__ float4 sp4[WAVES][F4PW];
    __shared__ float4 st4[WAVES][F4PW];

    const int tid  = threadIdx.x;
    const int wave = tid >> 6;
    const int lane = tid & 63;
    const size_t base4 = (size_t)blockIdx.x * (WAVES * F4PW) + (size_t)wave * F4PW;

    // Coalesced staging into this wave's own segment. 480 = 7.5 * 64.
#pragma unroll
    for (int i = 0; i < 8; ++i) {
        int k = i * 64 + lane;
        if (i < 7 || lane < 32) {
            sp4[wave][k] = pred4[base4 + k];
            st4[wave][k] = tgt4[base4 + k];
        }
    }
    // Same-wave ds_write -> ds_read: only need ordering + lgkmcnt, NOT s_barrier.
    __threadfence_block();

    const float invB = 1.0f / 8192.0f;
    int cg = blockIdx.x * BLOCK + tid;        // global cell index
    unsigned cell = (unsigned)cg % 49u;
    float fi = (float)(cell / 7u);
    float fj = (float)(cell % 7u);

    const float* p = (const float*)(&sp4[wave][0]) + lane * 30;
    const float* t = (const float*)(&st4[wave][0]) + lane * 30;

    float pl[30], tl[30];
#pragma unroll
    for (int k = 0; k < 30; ++k) { pl[k] = p[k]; tl[k] = t[k]; }

    bool obj = tl[4] > 0.0f;                  // target[...,4] is exactly 1.0 or 0.0

    float iou1 = iou_fn(tl, pl, fi, fj);      // pred box 1
    float iou2 = iou_fn(tl, pl + 5, fi, fj);  // pred box 2
    bool choose1 = iou1 > iou2;
    float m1 = (obj && choose1 && (iou1 != 0.0f)) ? 1.0f : 0.0f;
    float m2 = (obj && !choose1 && (iou2 != 0.0f)) ? 1.0f : 0.0f;

    float obj_loss = m1 * sq(iou1 - pl[4]) + m2 * sq(iou2 - pl[9]);

    float xy = m1 * (sq(tl[0] - pl[0]) + sq(tl[1] - pl[1]))
             + m2 * (sq(tl[5] - pl[5]) + sq(tl[6] - pl[6]));

    float wh = m1 * (sq(sqrtf(tl[2]) - sqrtf(pl[2])) + sq(sqrtf(tl[3]) - sqrtf(pl[3])))
             + m2 * (sq(sqrtf(tl[7]) - sqrtf(pl[7])) + sq(sqrtf(tl[8]) - sqrtf(pl[8])));

    float noobj = 0.0f;
#pragma unroll
    for (int k = 0; k < 6; ++k) {
        int ci = 4 + 5 * k;
        noobj += sq(tl[ci] - pl[ci]);
    }
    if (obj) noobj = 0.0f;

    float clsum = 0.0f;
#pragma unroll
    for (int k = 10; k < 30; ++k) clsum += sq(pl[k] - tl[k]);
    if (!obj) clsum = 0.0f;

    float conf = (obj_loss + 0.5f * noobj) * invB;
    float reg  = 5.0f * (xy + wh) * invB;
    float cls  = clsum * invB;

    // wave-64 shuffle reduction
#pragma unroll
    for (int off = 32; off > 0; off >>= 1) {
        conf += __shfl_down(conf, off, 64);
        reg  += __shfl_down(reg,  off, 64);
        cls  += __shfl_down(cls,  off, 64);
    }

    if (USE_WS) {
        // Scattered atomics (64 line-padded slots) + ticket; last wave writes out.
        unsigned tkt = 0;
        float* slot = partials + (size_t)(blockIdx.x & (NSLOT - 1)) * 16;
        if (lane == 0) {
            atomicAdd(&slot[0], conf);
            atomicAdd(&slot[1], reg);
            atomicAdd(&slot[2], cls);
            __threadfence();
            tkt = atomicAdd(counter, 1u);
        }
        tkt = __shfl(tkt, 0, 64);
        if (tkt == (unsigned)(nticket - 1)) {   // globally last wave
            __threadfence();
            float v0 = 0.0f, v1 = 0.0f, v2 = 0.0f;
            if (lane < NSLOT) {
                float* s2 = partials + (size_t)lane * 16;
                v0 = atomicAdd(&s2[0], 0.0f);   // coherent device-scope reads
                v1 = atomicAdd(&s2[1], 0.0f);
                v2 = atomicAdd(&s2[2], 0.0f);
            }
#pragma unroll
            for (int off = 32; off > 0; off >>= 1) {
                v0 += __shfl_down(v0, off, 64);
                v1 += __shfl_down(v1, off, 64);
                v2 += __shfl_down(v2, off, 64);
            }
            if (lane == 0) { out[0] = v0; out[1] = v1; out[2] = v2; }
        }
    } else {
        if (lane == 0) {
            atomicAdd(&out[0], conf);
            atomicAdd(&out[1], reg);
            atomicAdd(&out[2], cls);
        }
    }
}

extern "C" void kernel_launch(void* const* d_in, const int* in_sizes, int n_in,
                              void* d_out, int out_size, void* d_ws, size_t ws_size,
                              hipStream_t stream) {
    const float4* pred4 = (const float4*)d_in[0];
    const float4* tgt4  = (const float4*)d_in[1];
    float* out = (float*)d_out;

    const int grid = NCELLS / BLOCK;           // 1568
    const size_t need = (size_t)NSLOT * 16 * sizeof(float) + sizeof(unsigned);

    if (ws_size >= need) {
        float* partials = (float*)d_ws;
        unsigned* counter = (unsigned*)((char*)d_ws + NSLOT * 16 * sizeof(float));
        hipMemsetAsync(d_ws, 0, need, stream);  // zero slots + ticket (ws is poisoned)
        yolo_loss_kernel<true><<<grid, BLOCK, 0, stream>>>(
            pred4, tgt4, partials, counter, out, grid * WAVES);
    } else {
        hipMemsetAsync(out, 0, 3 * sizeof(float), stream);
        yolo_loss_kernel<false><<<grid, BLOCK, 0, stream>>>(
            pred4, tgt4, nullptr, nullptr, out, grid * WAVES);
    }
}

// Round 4
// 114.918 us; speedup vs baseline: 2.0793x; 2.0793x over previous
//
#include <hip/hip_runtime.h>

#define NCELLS (8192 * 7 * 7)   // 401408 = 1568 * 256 exactly
#define BLOCK 256
#define NSLOT 256               // 16B-padded partial slots (disjoint cache lines enough: 4KB spread)

__device__ __forceinline__ float sq(float x) { return x * x; }

__device__ __forceinline__ float iou_fn(const float* t, const float* p, float fi, float fj) {
    const float STEP = 1.0f / 7.0f;
    float w1 = t[2], h1 = t[3];
    float x1 = (t[0] + fj) * STEP, y1 = (t[1] + fi) * STEP;
    float a1 = fmaxf(x1 - w1 * 0.5f, 0.0f);
    float b1 = fmaxf(y1 - h1 * 0.5f, 0.0f);
    float w2 = p[2], h2 = p[3];
    float x2 = (p[0] + fj) * STEP, y2 = (p[1] + fi) * STEP;
    float a2 = fmaxf(x2 - w2 * 0.5f, 0.0f);
    float b2 = fmaxf(y2 - h2 * 0.5f, 0.0f);
    float iw = w1 + w2 - (fmaxf(a1 + w1, a2 + w2) - fminf(a1, a2));
    float ih = h1 + h2 - (fmaxf(b1 + h1, b2 + h2) - fminf(b1, b2));
    bool valid = (iw > 0.0f) && (ih > 0.0f);
    float inter = valid ? iw * ih : 0.0f;
    float uni = w1 * h1 + w2 * h2 - inter;
    return valid ? inter / uni : 0.0f;
}

// Pass 1: identical to the R1 kernel (70us) EXCEPT the final atomics go to
// 256 scattered slots in d_ws instead of one shared cache line in d_out.
__global__ __launch_bounds__(BLOCK) void yolo_part_kernel(
        const float* __restrict__ pred, const float* __restrict__ target,
        float* __restrict__ partials) {
    const float invB = 1.0f / 8192.0f;
    int c = blockIdx.x * BLOCK + threadIdx.x;   // grid sized exactly; no tail

    unsigned cell = (unsigned)c % 49u;
    float fi = (float)(cell / 7u);
    float fj = (float)(cell % 7u);

    const float* p = pred + (size_t)c * 30;
    const float* t = target + (size_t)c * 30;

    float pl[30], tl[30];
#pragma unroll
    for (int k = 0; k < 15; ++k) {              // cells are 8B-aligned -> float2 OK
        float2 pv = ((const float2*)p)[k];
        float2 tv = ((const float2*)t)[k];
        pl[2 * k] = pv.x; pl[2 * k + 1] = pv.y;
        tl[2 * k] = tv.x; tl[2 * k + 1] = tv.y;
    }

    bool obj = tl[4] > 0.0f;                    // target[...,4] is exactly 1.0 or 0.0

    float iou1 = iou_fn(tl, pl, fi, fj);
    float iou2 = iou_fn(tl, pl + 5, fi, fj);
    bool choose1 = iou1 > iou2;
    float m1 = (obj && choose1 && (iou1 != 0.0f)) ? 1.0f : 0.0f;
    float m2 = (obj && !choose1 && (iou2 != 0.0f)) ? 1.0f : 0.0f;

    float obj_loss = m1 * sq(iou1 - pl[4]) + m2 * sq(iou2 - pl[9]);

    float xy = m1 * (sq(tl[0] - pl[0]) + sq(tl[1] - pl[1]))
             + m2 * (sq(tl[5] - pl[5]) + sq(tl[6] - pl[6]));

    float wh = m1 * (sq(sqrtf(tl[2]) - sqrtf(pl[2])) + sq(sqrtf(tl[3]) - sqrtf(pl[3])))
             + m2 * (sq(sqrtf(tl[7]) - sqrtf(pl[7])) + sq(sqrtf(tl[8]) - sqrtf(pl[8])));

    float noobj = 0.0f;
#pragma unroll
    for (int k = 0; k < 6; ++k) {
        int ci = 4 + 5 * k;                     // 4, 9, 14, 19, 24, 29
        noobj += sq(tl[ci] - pl[ci]);
    }
    if (obj) noobj = 0.0f;

    float clsum = 0.0f;
#pragma unroll
    for (int k = 10; k < 30; ++k) clsum += sq(pl[k] - tl[k]);
    if (!obj) clsum = 0.0f;

    float conf = (obj_loss + 0.5f * noobj) * invB;
    float reg  = 5.0f * (xy + wh) * invB;
    float cls  = clsum * invB;

#pragma unroll
    for (int off = 32; off > 0; off >>= 1) {
        conf += __shfl_down(conf, off, 64);
        reg  += __shfl_down(reg,  off, 64);
        cls  += __shfl_down(cls,  off, 64);
    }

    __shared__ float s[3][4];
    int lane = threadIdx.x & 63;
    int wave = threadIdx.x >> 6;
    if (lane == 0) { s[0][wave] = conf; s[1][wave] = reg; s[2][wave] = cls; }
    __syncthreads();
    if (threadIdx.x == 0) {
        // ~18 staggered RMWs per slot instead of 4704 on one line
        float* slot = partials + (size_t)(blockIdx.x & (NSLOT - 1)) * 4;
        atomicAdd(&slot[0], s[0][0] + s[0][1] + s[0][2] + s[0][3]);
        atomicAdd(&slot[1], s[1][0] + s[1][1] + s[1][2] + s[1][3]);
        atomicAdd(&slot[2], s[2][0] + s[2][1] + s[2][2] + s[2][3]);
    }
}

// Pass 2: one block folds the 256 slots and writes the 3 outputs.
// Kernel-boundary on the stream guarantees visibility of pass-1 atomics.
__global__ __launch_bounds__(BLOCK) void yolo_final_kernel(
        const float4* __restrict__ partials, float* __restrict__ out) {
    int tid = threadIdx.x;
    float4 v = partials[tid];                   // 256 x 16B, coalesced
    float a = v.x, b = v.y, d = v.z;
#pragma unroll
    for (int off = 32; off > 0; off >>= 1) {
        a += __shfl_down(a, off, 64);
        b += __shfl_down(b, off, 64);
        d += __shfl_down(d, off, 64);
    }
    __shared__ float s[3][4];
    int lane = tid & 63;
    int wave = tid >> 6;
    if (lane == 0) { s[0][wave] = a; s[1][wave] = b; s[2][wave] = d; }
    __syncthreads();
    if (tid == 0) {
        out[0] = s[0][0] + s[0][1] + s[0][2] + s[0][3];
        out[1] = s[1][0] + s[1][1] + s[1][2] + s[1][3];
        out[2] = s[2][0] + s[2][1] + s[2][2] + s[2][3];
    }
}

extern "C" void kernel_launch(void* const* d_in, const int* in_sizes, int n_in,
                              void* d_out, int out_size, void* d_ws, size_t ws_size,
                              hipStream_t stream) {
    const float* pred   = (const float*)d_in[0];
    const float* target = (const float*)d_in[1];
    float* out = (float*)d_out;
    float* partials = (float*)d_ws;             // NSLOT * 4 floats = 4 KB

    // d_ws is poisoned to 0xAA before every launch — zero the slots (capture-safe)
    hipMemsetAsync(d_ws, 0, NSLOT * 4 * sizeof(float), stream);

    int grid = NCELLS / BLOCK;                  // exact: 1568
    yolo_part_kernel<<<grid, BLOCK, 0, stream>>>(pred, target, partials);
    yolo_final_kernel<<<1, BLOCK, 0, stream>>>((const float4*)partials, out);
}